// Round 3
// baseline (2097.498 us; speedup 1.0000x reference)
//
#include <hip/hip_runtime.h>
#include <math.h>

#define NCLS 19
#define NPROTO 10
#define KM 190
#define KMP 192
#define D 720
#define BM 128
#define CHK 16
#define NCHK 45

typedef __bf16 bf16x8 __attribute__((ext_vector_type(8)));
typedef float f32x16 __attribute__((ext_vector_type(16)));

__device__ __forceinline__ float wred_sum(float v) {
#pragma unroll
  for (int o = 32; o > 0; o >>= 1) v += __shfl_xor(v, o, 64);
  return v;
}
__device__ __forceinline__ float wred_max(float v) {
#pragma unroll
  for (int o = 32; o > 0; o >>= 1) v = fmaxf(v, __shfl_xor(v, o, 64));
  return v;
}
__device__ __forceinline__ double wred_sumd(double v) {
#pragma unroll
  for (int o = 32; o > 0; o >>= 1) v += __shfl_xor(v, o, 64);
  return v;
}

// bf16 RTNE high part; returns bits, writes back the fp32 value of hi
__device__ __forceinline__ ushort bf_hi(float v, float& hf) {
  const uint u = __float_as_uint(v);
  const uint r = (u + 0x7FFFu + ((u >> 16) & 1u)) >> 16;
  hf = __uint_as_float(r << 16);
  return (ushort)r;
}

// ---------------- fused prep: blocks 0..191 = proto split (hi/lo bf16 in
// chunk-staging order); block 192 = G2/GB/C3.
// pgtb offset(ushort) = c*6144 + ((src*2+kb)*192 + col)*8 + e, d = c*16+kb*8+e.
__global__ void prep_all(const float* __restrict__ pr, const float* __restrict__ fg,
                         const float* __restrict__ fb, ushort* __restrict__ pgtb,
                         float* __restrict__ Av, float* __restrict__ Bv,
                         float* __restrict__ G2, float* __restrict__ GB,
                         float* __restrict__ C3) {
  const int j = blockIdx.x, lane = threadIdx.x;
  if (j == KMP) {  // gamma/beta prep (one wave)
    float cg = 0.f, cgb = 0.f, cb = 0.f;
#pragma unroll
    for (int jj = 0; jj < 12; ++jj) {
      const int d2 = lane + 64 * jj;
      if (d2 < D) {
        const float g = fg[d2], b = fb[d2];
        G2[d2] = g * g;
        GB[d2] = g * b;
        cg = fmaf(g, g, cg);
        cgb = fmaf(g, b, cgb);
        cb = fmaf(b, b, cb);
      }
    }
    cg = wred_sum(cg); cgb = wred_sum(cgb); cb = wred_sum(cb);
    if (lane == 0) { C3[0] = cg; C3[1] = cgb; C3[2] = cb; }
    return;
  }
  if (j >= KM) {  // zero pad columns 190,191
#pragma unroll
    for (int jj = 0; jj < 12; ++jj) {
      const int d2 = lane + 64 * jj;
      if (d2 < D) {
        const int c = d2 >> 4, kb = (d2 >> 3) & 1, e = d2 & 7;
        const size_t b0 = (size_t)c * 6144 + (size_t)kb * KMP * 8 + (size_t)j * 8 + e;
        pgtb[b0] = 0;
        pgtb[b0 + 2 * KMP * 8] = 0;
      }
    }
    if (lane == 0) { Av[j] = 0.f; Bv[j] = 0.f; }
    return;
  }
  float pv[12];
  float sp = 0.f;
#pragma unroll
  for (int jj = 0; jj < 12; ++jj) {
    const int d2 = lane + 64 * jj;
    pv[jj] = (d2 < D) ? pr[(size_t)j * D + d2] : 0.f;
    sp = fmaf(pv[jj], pv[jj], sp);
  }
  sp = wred_sum(sp);
  const float ip = 1.f / fmaxf(sqrtf(sp), 1e-12f);
  float sa = 0.f, sb = 0.f;
#pragma unroll
  for (int jj = 0; jj < 12; ++jj) {
    const int d2 = lane + 64 * jj;
    if (d2 < D) {
      const float ph = pv[jj] * ip;
      const float g = fg[d2], b = fb[d2];
      const float val = g * ph;
      float hf, dummy;
      const ushort h = bf_hi(val, hf);
      const ushort l = bf_hi(val - hf, dummy);
      const int c = d2 >> 4, kb = (d2 >> 3) & 1, e = d2 & 7;
      const size_t b0 = (size_t)c * 6144 + (size_t)kb * KMP * 8 + (size_t)j * 8 + e;
      pgtb[b0] = h;
      pgtb[b0 + 2 * KMP * 8] = l;
      sa = fmaf(g, ph, sa);
      sb = fmaf(b, ph, sb);
    }
  }
  sa = wred_sum(sa); sb = wred_sum(sb);
  if (lane == 0) { Av[j] = sa; Bv[j] = sb; }
}

// ---------------- main pass: split-bf16 MFMA GEMM + per-pixel affine fixup.
// Writes TRUE cosine sims into the contrast buffer (normalized later in place)
// and MU/RS/IL per pixel. BM=128, 4 waves (2m x 2n), wave tile 64x96.
__global__ __launch_bounds__(256, 3) void gemm_main(
    const float* __restrict__ x, const ushort* __restrict__ pgtb,
    const float* __restrict__ Av, const float* __restrict__ Bv,
    const float* __restrict__ G2, const float* __restrict__ GB,
    const float* __restrict__ C3, float* __restrict__ simC,
    float* __restrict__ MUg, float* __restrict__ RSg, float* __restrict__ ILg,
    int N) {
  __shared__ __align__(16) union {
    struct {
      ushort X[2][2][2][BM][8];   // [buf][src][kb][pix][8]  16384 B
      ushort P[2][2][2][KMP][8];  // [buf][src][kb][col][8]  24576 B
    } g;
    float ST[5][2][BM];           // stats partials alias (4096 B)
  } U;
  __shared__ float A_s[KMP], B_s[KMP];
  __shared__ float MU[BM], RS[BM], IL[BM];

  const int t = threadIdx.x;
  const int n0 = blockIdx.x * BM;
  const int w = t >> 6, lane = t & 63;
  const int wm = w >> 1, wn = w & 1;  // wave tile rows [64wm,+64), cols [96wn,+96)
  const int l31 = lane & 31, lhi = lane >> 5;
  const int p = t & 127, h = t >> 7;  // staging: pixel, d-half (8 elems each)

  if (t < KMP) { A_s[t] = Av[t]; B_s[t] = Bv[t]; }

  f32x16 acc[2][3];
#pragma unroll
  for (int mr = 0; mr < 2; ++mr)
#pragma unroll
    for (int nt = 0; nt < 3; ++nt)
#pragma unroll
      for (int e = 0; e < 16; ++e) acc[mr][nt][e] = 0.f;

  float s0 = 0.f, qq = 0.f, s1 = 0.f, s2 = 0.f, s3 = 0.f;

  const float* xrow = x + (size_t)(n0 + p) * D + 8 * h;

  // convert 8 x-values -> hi/lo bf16, accumulate stats, write LDS
  auto stageX = [&](int nb, int c, const float4& xa, const float4& xb) {
    const int d0 = c * CHK + 8 * h;
    const float4 g2a = *(const float4*)&G2[d0];
    const float4 g2b = *(const float4*)&G2[d0 + 4];
    const float4 gba = *(const float4*)&GB[d0];
    const float4 gbb = *(const float4*)&GB[d0 + 4];
    const float v[8] = {xa.x, xa.y, xa.z, xa.w, xb.x, xb.y, xb.z, xb.w};
    const float gg[8] = {g2a.x, g2a.y, g2a.z, g2a.w, g2b.x, g2b.y, g2b.z, g2b.w};
    const float gv[8] = {gba.x, gba.y, gba.z, gba.w, gbb.x, gbb.y, gbb.z, gbb.w};
    ushort hh[8], ll[8];
#pragma unroll
    for (int e = 0; e < 8; ++e) {
      const float xv = v[e];
      float hf, dm;
      hh[e] = bf_hi(xv, hf);
      ll[e] = bf_hi(xv - hf, dm);
      s0 += xv;
      const float xx = xv * xv;
      qq += xx;
      s1 = fmaf(xv, gg[e], s1);
      s2 = fmaf(xx, gg[e], s2);
      s3 = fmaf(xv, gv[e], s3);
    }
    *(uint4*)&U.g.X[nb][0][h][p][0] =
        make_uint4((uint)hh[0] | ((uint)hh[1] << 16), (uint)hh[2] | ((uint)hh[3] << 16),
                   (uint)hh[4] | ((uint)hh[5] << 16), (uint)hh[6] | ((uint)hh[7] << 16));
    *(uint4*)&U.g.X[nb][1][h][p][0] =
        make_uint4((uint)ll[0] | ((uint)ll[1] << 16), (uint)ll[2] | ((uint)ll[3] << 16),
                   (uint)ll[4] | ((uint)ll[5] << 16), (uint)ll[6] | ((uint)ll[7] << 16));
  };

  // per-acc-element K-order: hh, hl, lh per chunk (bitwise same as prior rounds)
  auto mfmaStep = [&](int bf) {
    const int row0 = 64 * wm + l31;
    const bf16x8 ah0 = *reinterpret_cast<const bf16x8*>(&U.g.X[bf][0][lhi][row0][0]);
    const bf16x8 ah1 = *reinterpret_cast<const bf16x8*>(&U.g.X[bf][0][lhi][row0 + 32][0]);
    const bf16x8 al0 = *reinterpret_cast<const bf16x8*>(&U.g.X[bf][1][lhi][row0][0]);
    const bf16x8 al1 = *reinterpret_cast<const bf16x8*>(&U.g.X[bf][1][lhi][row0 + 32][0]);
#pragma unroll
    for (int nt = 0; nt < 3; ++nt) {
      const int col = 96 * wn + 32 * nt + l31;
      const bf16x8 bh = *reinterpret_cast<const bf16x8*>(&U.g.P[bf][0][lhi][col][0]);
      const bf16x8 bl = *reinterpret_cast<const bf16x8*>(&U.g.P[bf][1][lhi][col][0]);
      acc[0][nt] = __builtin_amdgcn_mfma_f32_32x32x16_bf16(ah0, bh, acc[0][nt], 0, 0, 0);
      acc[1][nt] = __builtin_amdgcn_mfma_f32_32x32x16_bf16(ah1, bh, acc[1][nt], 0, 0, 0);
      acc[0][nt] = __builtin_amdgcn_mfma_f32_32x32x16_bf16(ah0, bl, acc[0][nt], 0, 0, 0);
      acc[1][nt] = __builtin_amdgcn_mfma_f32_32x32x16_bf16(ah1, bl, acc[1][nt], 0, 0, 0);
      acc[0][nt] = __builtin_amdgcn_mfma_f32_32x32x16_bf16(al0, bh, acc[0][nt], 0, 0, 0);
      acc[1][nt] = __builtin_amdgcn_mfma_f32_32x32x16_bf16(al1, bh, acc[1][nt], 0, 0, 0);
    }
  };

  // prologue: stage chunk 0 into buf 0
  {
    const uint4* ps = (const uint4*)pgtb;
    const uint4 p0 = ps[t], p1 = ps[t + 256], p2 = ps[t + 512];
    const float4 xa = *(const float4*)xrow;
    const float4 xb = *(const float4*)(xrow + 4);
    uint4* pd = (uint4*)&U.g.P[0][0][0][0][0];
    pd[t] = p0; pd[t + 256] = p1; pd[t + 512] = p2;
    stageX(0, 0, xa, xb);
  }
  __syncthreads();

  for (int c = 0; c < NCHK; ++c) {
    const int buf = c & 1;
    const bool pf = (c + 1 < NCHK);
    uint4 p0, p1, p2;
    float4 xa, xb;
    if (pf) {
      const uint4* ps = (const uint4*)(pgtb + (size_t)(c + 1) * 6144);
      p0 = ps[t]; p1 = ps[t + 256]; p2 = ps[t + 512];
      xa = *(const float4*)(xrow + (c + 1) * CHK);
      xb = *(const float4*)(xrow + (c + 1) * CHK + 4);
    }
    mfmaStep(buf);
    if (pf) {
      uint4* pd = (uint4*)&U.g.P[buf ^ 1][0][0][0][0];
      pd[t] = p0; pd[t + 256] = p1; pd[t + 512] = p2;
      stageX(buf ^ 1, c + 1, xa, xb);
    }
    __syncthreads();
  }

  // per-pixel stats reduction (2 threads per pixel); ST aliases dead staging
  U.ST[0][h][p] = s0;
  U.ST[1][h][p] = qq;
  U.ST[2][h][p] = s1;
  U.ST[3][h][p] = s2;
  U.ST[4][h][p] = s3;
  __syncthreads();
  if (t < BM) {
    const float S0 = U.ST[0][0][t] + U.ST[0][1][t];
    const float Q = U.ST[1][0][t] + U.ST[1][1][t];
    const float S1 = U.ST[2][0][t] + U.ST[2][1][t];
    const float S2 = U.ST[3][0][t] + U.ST[3][1][t];
    const float S3 = U.ST[4][0][t] + U.ST[4][1][t];
    const float Cgg = C3[0], Cgb = C3[1], Cbb = C3[2];
    const float mu = S0 / 720.f;
    const float var = Q / 720.f - mu * mu;
    const float rs = 1.f / sqrtf(var + 1e-5f);
    const float L2v = rs * rs * (S2 - 2.f * mu * S1 + mu * mu * Cgg) +
                      2.f * rs * (S3 - mu * Cgb) + Cbb;
    const float il = 1.f / fmaxf(sqrtf(fmaxf(L2v, 0.f)), 1e-12f);
    MU[t] = mu; RS[t] = rs; IL[t] = il;
    MUg[n0 + t] = mu; RSg[n0 + t] = rs; ILg[n0 + t] = il;
  }
  __syncthreads();

  // fixup to true cosine sims, store straight to the contrast buffer
  float aC[3], bC[3];
#pragma unroll
  for (int nt = 0; nt < 3; ++nt) {
    const int col = 96 * wn + 32 * nt + l31;
    aC[nt] = A_s[col];
    bC[nt] = B_s[col];
  }
#pragma unroll
  for (int mr = 0; mr < 2; ++mr)
#pragma unroll
    for (int rg = 0; rg < 16; ++rg) {
      const int r = 64 * wm + 32 * mr + (rg & 3) + 8 * (rg >> 2) + 4 * lhi;
      const float mu = MU[r], rs = RS[r], il = IL[r];
#pragma unroll
      for (int nt = 0; nt < 3; ++nt) {
        const int col = 96 * wn + 32 * nt + l31;
        if (col < KM)
          simC[(size_t)(n0 + r) * KM + col] =
              (rs * (acc[mr][nt][rg] - mu * aC[nt]) + bC[nt]) * il;
      }
    }
}

// ---------------- epilogue: in-place LN-190 on contrast, out_seg, se, flags.
// Each block owns 64 rows exclusively -> in-place safe.
__global__ __launch_bounds__(256) void epilogue(
    float* __restrict__ co, const int* __restrict__ gt,
    float* __restrict__ out_seg, float* __restrict__ se, int* __restrict__ flags,
    const float* __restrict__ mn_g, const float* __restrict__ mn_b,
    const float* __restrict__ pn_g, const float* __restrict__ pn_b, int N) {
  __shared__ float PGn[KMP], PBn[KMP], MGn[32], MBn[32];
  __shared__ float rowbuf[4][KMP];
  const int t = threadIdx.x, w = t >> 6, lane = t & 63;
  if (t < KM) { PGn[t] = pn_g[t]; PBn[t] = pn_b[t]; }
  if (t < NCLS) { MGn[t] = mn_g[t]; MBn[t] = mn_b[t]; }
  __syncthreads();
  const int n0 = blockIdx.x * 64;
  const int j0 = lane, j1 = lane + 64, j2 = lane + 128;
  const bool ok2 = (j2 < KM);
  for (int pi = 0; pi < 16; ++pi) {
    const int n = n0 + w * 16 + pi;
    float* crow = &co[(size_t)n * KM];
    const float sv0 = crow[j0];
    const float sv1 = crow[j1];
    const float sv2 = ok2 ? crow[j2] : 0.f;
    float sum = wred_sum(sv0 + sv1 + sv2);
    const float mu = sum / 190.f;
    const float d0v = sv0 - mu, d1v = sv1 - mu, d2v = ok2 ? (sv2 - mu) : 0.f;
    float vs = wred_sum(d0v * d0v + d1v * d1v + d2v * d2v);
    const float rstd = 1.f / sqrtf(vs / 190.f + 1e-5f);
    // stash raw sims (wave-local) before overwriting
    rowbuf[w][j0] = sv0;
    rowbuf[w][j1] = sv1;
    if (ok2) rowbuf[w][j2] = sv2;
    const int g0 = gt[n], b10 = g0 * 10;
    if (j0 >= b10 && j0 < b10 + 10) se[(size_t)n * 10 + (j0 - b10)] = sv0;
    if (j1 >= b10 && j1 < b10 + 10) se[(size_t)n * 10 + (j1 - b10)] = sv1;
    if (ok2 && j2 >= b10 && j2 < b10 + 10) se[(size_t)n * 10 + (j2 - b10)] = sv2;
    crow[j0] = d0v * rstd * PGn[j0] + PBn[j0];
    crow[j1] = d1v * rstd * PGn[j1] + PBn[j1];
    if (ok2) crow[j2] = d2v * rstd * PGn[j2] + PBn[j2];
    // per-class max + LN over 19 -> out_seg, pred
    float mx = -3.0e38f;
    if (lane < NCLS) {
      const float* row = &rowbuf[w][lane * 10];
#pragma unroll
      for (int m2 = 0; m2 < 10; ++m2) mx = fmaxf(mx, row[m2]);
    }
    float s19 = wred_sum(lane < NCLS ? mx : 0.f);
    const float mu19 = s19 / 19.f;
    const float dv = (lane < NCLS) ? (mx - mu19) : 0.f;
    float v19 = wred_sum(dv * dv);
    const float rs19 = 1.f / sqrtf(v19 / 19.f + 1e-5f);
    float key = -3.0e38f;
    if (lane < NCLS) {
      const float os = dv * rs19 * MGn[lane] + MBn[lane];
      out_seg[(size_t)n * NCLS + lane] = os;
      key = os;
    }
    const float kmax = wred_max(key);
    const unsigned long long bm = __ballot(key == kmax);
    const int pred = __ffsll((unsigned long long)bm) - 1;
    if (lane == 0) flags[n] = (pred == g0) ? 1 : 0;
  }
}

// ---------------- fused Sinkhorn: one block per class, 3 rounds + final.
__global__ __launch_bounds__(1024) void sk_all(
    const float* __restrict__ se, const int* __restrict__ gt,
    const int* __restrict__ flags, float* __restrict__ ptgt,
    int* __restrict__ list, int* __restrict__ cnt, int N) {
  const int k = blockIdx.x;
  const int t = threadIdx.x, w = t >> 6, lane = t & 63;
  __shared__ double CS[16][10];
  __shared__ float u_s[10];
  for (int pass = 0; pass < 3; ++pass) {
    double cs[10];
#pragma unroll
    for (int m = 0; m < 10; ++m) cs[m] = 0.0;
    for (int n = t; n < N; n += 1024) {
      if (gt[n] != k) continue;
      float e[10];
      const float2* sp2 = (const float2*)&se[(size_t)n * 10];
#pragma unroll
      for (int m2 = 0; m2 < 5; ++m2) {
        const float2 v = sp2[m2];
        e[2 * m2] = expf(v.x / 0.05f);
        e[2 * m2 + 1] = expf(v.y / 0.05f);
      }
      float a = 1.f;
      if (pass > 0) {
        float s = 0.f;
#pragma unroll
        for (int m = 0; m < 10; ++m) s += e[m] * u_s[m];
        a = (s > 0.f) ? 1.f / s : 0.f;
      }
#pragma unroll
      for (int m = 0; m < 10; ++m) cs[m] += (double)(a * e[m]);
    }
#pragma unroll
    for (int m = 0; m < 10; ++m) cs[m] = wred_sumd(cs[m]);
    if (lane == 0)
#pragma unroll
      for (int m = 0; m < 10; ++m) CS[w][m] = cs[m];
    __syncthreads();
    if (t < 10) {
      double s = 0.0;
#pragma unroll
      for (int ww = 0; ww < 16; ++ww) s += CS[ww][t];
      u_s[t] = (s > 0.0) ? (float)(1.0 / (10.0 * s)) : 0.f;
    }
    __syncthreads();
  }
  // final: hard assignment + list of correct pixels
  for (int n = t; n < N; n += 1024) {
    if (gt[n] != k) continue;
    float best = -1.f;
    int bi = 0;
#pragma unroll
    for (int m = 0; m < 10; ++m) {
      const float v = expf(se[(size_t)n * 10 + m] / 0.05f) * u_s[m];
      if (v > best) { best = v; bi = m; }
    }
    ptgt[n] = (float)(bi + 10 * k);
    if (flags[n]) {
      const int pos = atomicAdd(cnt, 1);
      list[pos] = n | (bi << 20) | (k << 24);
    }
  }
}

// ---------------- fused f-accumulation + prototype update (block per proto)
__global__ __launch_bounds__(256) void proto_update(
    const float* __restrict__ pr, const float* __restrict__ x,
    const float* __restrict__ fg, const float* __restrict__ fb,
    const float* __restrict__ MUg, const float* __restrict__ RSg,
    const float* __restrict__ ILg, const int* __restrict__ list,
    const int* __restrict__ cnt, float* __restrict__ out) {
  const int j = blockIdx.x;  // 0..189
  const int t = threadIdx.x, w = t >> 6, lane = t & 63;
  const int tag = ((j / 10) << 4) | (j % 10);  // == packed >> 20
  const int d0 = t, d1 = t + 256, d2 = t + 512;
  const bool has2 = (d2 < D);
  const float fg0 = fg[d0], fb0 = fb[d0];
  const float fg1 = fg[d1], fb1 = fb[d1];
  const float fg2 = has2 ? fg[d2] : 0.f, fb2 = has2 ? fb[d2] : 0.f;
  float fa0 = 0.f, fa1 = 0.f, fa2 = 0.f;
  __shared__ int nlist[4096];
  __shared__ int nmatch;
  __shared__ float RP[4], RF[4], RV[4];
  const int total = *cnt;
  int hits = 0;
  for (int base = 0; base < total; base += 4096) {
    const int hi = min(base + 4096, total);
    if (t == 0) nmatch = 0;
    __syncthreads();
    for (int i = base + t; i < hi; i += 256) {
      const int pk = list[i];
      if ((pk >> 20) == tag) {
        const int pos = atomicAdd(&nmatch, 1);
        nlist[pos] = pk & 0xFFFFF;
      }
    }
    __syncthreads();
    const int nm = nmatch;
    hits += nm;
    for (int ii = 0; ii < nm; ++ii) {
      const int n = nlist[ii];
      const float mu = MUg[n], rs = RSg[n], il = ILg[n];
      const float* xr = &x[(size_t)n * D];
      fa0 += ((xr[d0] - mu) * rs * fg0 + fb0) * il;
      fa1 += ((xr[d1] - mu) * rs * fg1 + fb1) * il;
      if (has2) fa2 += ((xr[d2] - mu) * rs * fg2 + fb2) * il;
    }
    __syncthreads();
  }
  const float pv0 = pr[(size_t)j * D + d0];
  const float pv1 = pr[(size_t)j * D + d1];
  const float pv2 = has2 ? pr[(size_t)j * D + d2] : 0.f;
  float sp = pv0 * pv0 + pv1 * pv1 + pv2 * pv2;
  float sf = fa0 * fa0 + fa1 * fa1 + fa2 * fa2;
  sp = wred_sum(sp); sf = wred_sum(sf);
  if (lane == 0) { RP[w] = sp; RF[w] = sf; }
  __syncthreads();
  sp = RP[0] + RP[1] + RP[2] + RP[3];
  sf = RF[0] + RF[1] + RF[2] + RF[3];
  const float ip = 1.f / fmaxf(sqrtf(sp), 1e-12f);
  const float iff = 1.f / fmaxf(sqrtf(sf), 1e-12f);
  const bool valid = hits > 0;
  const float ph0 = pv0 * ip, ph1 = pv1 * ip, ph2 = pv2 * ip;
  const float vv0 = valid ? 0.999f * ph0 + 0.001f * (fa0 * iff) : ph0;
  const float vv1 = valid ? 0.999f * ph1 + 0.001f * (fa1 * iff) : ph1;
  const float vv2 = valid ? 0.999f * ph2 + 0.001f * (fa2 * iff) : ph2;
  float sv = vv0 * vv0 + vv1 * vv1 + vv2 * vv2;
  sv = wred_sum(sv);
  if (lane == 0) RV[w] = sv;
  __syncthreads();
  sv = RV[0] + RV[1] + RV[2] + RV[3];
  const float ivv = 1.f / fmaxf(sqrtf(sv), 1e-12f);
  out[(size_t)j * D + d0] = vv0 * ivv;
  out[(size_t)j * D + d1] = vv1 * ivv;
  if (has2) out[(size_t)j * D + d2] = vv2 * ivv;
}

extern "C" void kernel_launch(void* const* d_in, const int* in_sizes, int n_in,
                              void* d_out, int out_size, void* d_ws, size_t ws_size,
                              hipStream_t stream) {
  const float* x = (const float*)d_in[0];
  const float* protos = (const float*)d_in[1];
  const float* fn_g = (const float*)d_in[2];
  const float* fn_b = (const float*)d_in[3];
  const float* mn_g = (const float*)d_in[4];
  const float* mn_b = (const float*)d_in[5];
  const float* pn_g = (const float*)d_in[6];
  const float* pn_b = (const float*)d_in[7];
  const int* gt = (const int*)d_in[8];
  const int N = in_sizes[0] / D;

  float* out_seg = (float*)d_out;
  float* contrast = out_seg + (size_t)N * NCLS;
  float* ptgt = contrast + (size_t)N * KM;
  float* pnew = ptgt + (size_t)N;

  char* ws = (char*)d_ws;
  size_t off = 0;
  auto alloc = [&](size_t bytes) {
    char* p = ws + off;
    off = (off + bytes + 255) & ~(size_t)255;
    return p;
  };
  ushort* pgtb = (ushort*)alloc((size_t)NCHK * 6144 * 2);  // 552960 B
  float* Av = (float*)alloc(KMP * 4);
  float* Bv = (float*)alloc(KMP * 4);
  float* G2 = (float*)alloc(D * 4);
  float* GB = (float*)alloc(D * 4);
  float* C3 = (float*)alloc(4 * 4);
  float* se = (float*)alloc((size_t)N * 10 * 4);
  float* MUg = (float*)alloc((size_t)N * 4);
  float* RSg = (float*)alloc((size_t)N * 4);
  float* ILg = (float*)alloc((size_t)N * 4);
  int* flags = (int*)alloc((size_t)N * 4);
  int* list = (int*)alloc((size_t)N * 4);
  int* cnt = (int*)alloc(256);

  hipMemsetAsync(cnt, 0, 4, stream);

  prep_all<<<KMP + 1, 64, 0, stream>>>(protos, fn_g, fn_b, pgtb, Av, Bv, G2, GB, C3);
  gemm_main<<<N / BM, 256, 0, stream>>>(x, pgtb, Av, Bv, G2, GB, C3, contrast,
                                        MUg, RSg, ILg, N);
  epilogue<<<N / 64, 256, 0, stream>>>(contrast, gt, out_seg, se, flags, mn_g,
                                       mn_b, pn_g, pn_b, N);
  sk_all<<<NCLS, 1024, 0, stream>>>(se, gt, flags, ptgt, list, cnt, N);
  proto_update<<<KM, 256, 0, stream>>>(protos, x, fn_g, fn_b, MUg, RSg, ILg,
                                       list, cnt, pnew);
}